// Round 1
// 178.445 us; speedup vs baseline: 1.0042x; 1.0042x over previous
//
#include <hip/hip_runtime.h>

#define AS1 __attribute__((address_space(1)))
#define AS3 __attribute__((address_space(3)))

using f32x4 = __attribute__((ext_vector_type(4))) float;
using s16x8 = __attribute__((ext_vector_type(8))) short;
using u16x4 = __attribute__((ext_vector_type(4))) unsigned short;
using u32x2 = __attribute__((ext_vector_type(2))) unsigned int;

__device__ __forceinline__ unsigned short f2bf(float f) {
  union { float f; unsigned u; } v; v.f = f;
  unsigned u = v.u;
  return (unsigned short)((u + 0x7FFFu + ((u >> 16) & 1u)) >> 16);  // RNE
}

__device__ __forceinline__ unsigned pack_bf2(float a, float b) {  // trunc; P in [0,1]
  union { float f; unsigned u; } x, y; x.f = a; y.f = b;
  return (x.u >> 16) | (y.u & 0xFFFF0000u);
}

__device__ __forceinline__ void load_lds16(const void* g, void* l) {
  __builtin_amdgcn_global_load_lds((const AS1 void*)g, (AS3 void*)l, 16, 0, 0);
}

// ---------------- fused prep: cast x + transpose both weights ----------------
__global__ __launch_bounds__(256) void prep_kernel(const float* __restrict__ x,
                                                   const float* __restrict__ w_qkv,
                                                   const float* __restrict__ w_proj,
                                                   unsigned short* __restrict__ xb,
                                                   unsigned short* __restrict__ wqkvT,
                                                   unsigned short* __restrict__ wprojT) {
  __shared__ float tile[32][33];
  const int bid = blockIdx.x, tid = threadIdx.x;
  if (bid < 4096) {
    int i = bid * 256 + tid;
    float4 v = ((const float4*)x)[i];
    u16x4 o;
    o.x = f2bf(v.x); o.y = f2bf(v.y); o.z = f2bf(v.z); o.w = f2bf(v.w);
    ((u16x4*)xb)[i] = o;
    return;
  }
  const float* in;
  unsigned short* out;
  int bx, by, R, C;
  if (bid < 7168) {
    int t = bid - 4096;
    bx = t % 96; by = t / 96; R = 1024; C = 3072;
    in = w_qkv; out = wqkvT;
  } else {
    int t = bid - 7168;
    bx = t % 32; by = t / 32; R = 1024; C = 1024;
    in = w_proj; out = wprojT;
  }
  const int tx = tid & 31, ty = tid >> 5;
  int xcol = bx * 32 + tx;
  int y0 = by * 32;
  for (int j = ty; j < 32; j += 8)
    tile[j][tx] = in[(size_t)(y0 + j) * C + xcol];
  __syncthreads();
  int x2 = by * 32 + tx;
  int y2 = bx * 32;
  for (int j = ty; j < 32; j += 8)
    out[(size_t)(y2 + j) * R + x2] = f2bf(tile[tx][j]);
}

// ---------------- V transpose: qkv V block [s][d] -> Vt[b][h][d][s] ----------------
__global__ __launch_bounds__(256) void transpose_v(const unsigned short* __restrict__ qkv,
                                                   unsigned short* __restrict__ Vt) {
  __shared__ unsigned short tile[64][65];
  const int tid = threadIdx.x;
  const int bh = blockIdx.y, b = bh >> 4, h = bh & 15;
  const int s0 = blockIdx.x * 64;
#pragma unroll
  for (int it = 0; it < 2; ++it) {
    int c = tid + it * 256;
    int row = c >> 3, cc = c & 7;
    s16x8 v = *(const s16x8*)(qkv + (size_t)(b * 2048 + s0 + row) * 3072 + 2048 + h * 64 + cc * 8);
#pragma unroll
    for (int j = 0; j < 8; ++j) tile[row][cc * 8 + j] = (unsigned short)v[j];
  }
  __syncthreads();
#pragma unroll
  for (int it = 0; it < 2; ++it) {
    int c = tid + it * 256;
    int d = c >> 3, sc = c & 7;
    s16x8 o;
#pragma unroll
    for (int j = 0; j < 8; ++j) o[j] = (short)tile[sc * 8 + j][d];
    *(s16x8*)(Vt + (size_t)bh * 64 * 2048 + (size_t)d * 2048 + s0 + sc * 8) = o;
  }
}

// ---------------- QKV GEMM: BK=64, XOR-swizzled LDS (conflict-free frag reads) ----------------
__global__ __launch_bounds__(256) void gemm_qkv(const unsigned short* __restrict__ A,
                                                const unsigned short* __restrict__ Bt,
                                                unsigned short* __restrict__ C,
                                                int M, int N, int K) {
  __shared__ unsigned short As[128 * 64];
  __shared__ unsigned short Bs[128 * 64];
  const int tid = threadIdx.x;
  const int wave = tid >> 6, lane = tid & 63;
  const int l15 = lane & 15, quad = lane >> 4;
  const int sx = l15 & 7;
  const int wm = wave & 1, wn = wave >> 1;
  const int bm = blockIdx.y, bn = blockIdx.x;

  f32x4 acc[4][4] = {};

  for (int k0 = 0; k0 < K; k0 += 64) {
    __syncthreads();
#pragma unroll
    for (int s = 0; s < 4; ++s) {
      int c = tid + s * 256;
      int row = c >> 3, cc = c & 7;
      int kc = (cc ^ (row & 7)) * 8;
      load_lds16(A + (size_t)(bm * 128 + row) * K + k0 + kc, As + c * 8);
      load_lds16(Bt + (size_t)(bn * 128 + row) * K + k0 + kc, Bs + c * 8);
    }
    __syncthreads();
#pragma unroll
    for (int kk = 0; kk < 2; ++kk) {
      s16x8 af[4], bfr[4];
#pragma unroll
      for (int i = 0; i < 4; ++i) {
        af[i]  = *(const s16x8*)(As + (wm * 64 + i * 16 + l15) * 64 + ((quad + 4 * kk) ^ sx) * 8);
        bfr[i] = *(const s16x8*)(Bs + (wn * 64 + i * 16 + l15) * 64 + ((quad + 4 * kk) ^ sx) * 8);
      }
#pragma unroll
      for (int i = 0; i < 4; ++i)
#pragma unroll
        for (int j = 0; j < 4; ++j)
          acc[i][j] = __builtin_amdgcn_mfma_f32_16x16x32_bf16(af[i], bfr[j], acc[i][j], 0, 0, 0);
    }
  }

  const int row0 = bm * 128 + wm * 64 + quad * 4;
  const int col0 = bn * 128 + wn * 64 + l15;
#pragma unroll
  for (int i = 0; i < 4; ++i)
#pragma unroll
    for (int j = 0; j < 4; ++j)
#pragma unroll
      for (int r = 0; r < 4; ++r)
        C[(size_t)(row0 + i * 16 + r) * N + (col0 + j * 16)] = f2bf(acc[i][j][r]);
}

// ---------------- proj GEMM: 128Mx64N, BK=64, swizzled; f32 out ----------------
__global__ __launch_bounds__(256) void gemm_proj(const unsigned short* __restrict__ A,
                                                 const unsigned short* __restrict__ Bt,
                                                 float* __restrict__ C,
                                                 int M, int N, int K) {
  __shared__ unsigned short As[128 * 64];
  __shared__ unsigned short Bs[64 * 64];
  const int tid = threadIdx.x;
  const int wave = tid >> 6, lane = tid & 63;
  const int l15 = lane & 15, quad = lane >> 4;
  const int sx = l15 & 7;
  const int wm = wave & 1, wn = wave >> 1;  // wn in 0..1
  const int bm = blockIdx.y, bn = blockIdx.x;

  f32x4 acc[4][2] = {};

  for (int k0 = 0; k0 < K; k0 += 64) {
    __syncthreads();
#pragma unroll
    for (int s = 0; s < 4; ++s) {
      int c = tid + s * 256;
      int row = c >> 3, cc = c & 7;
      int kc = (cc ^ (row & 7)) * 8;
      load_lds16(A + (size_t)(bm * 128 + row) * K + k0 + kc, As + c * 8);
    }
#pragma unroll
    for (int s = 0; s < 2; ++s) {
      int c = tid + s * 256;
      int row = c >> 3, cc = c & 7;
      int kc = (cc ^ (row & 7)) * 8;
      load_lds16(Bt + (size_t)(bn * 64 + row) * K + k0 + kc, Bs + c * 8);
    }
    __syncthreads();
#pragma unroll
    for (int kk = 0; kk < 2; ++kk) {
      s16x8 af[4], bfr[2];
#pragma unroll
      for (int i = 0; i < 4; ++i)
        af[i] = *(const s16x8*)(As + (wm * 64 + i * 16 + l15) * 64 + ((quad + 4 * kk) ^ sx) * 8);
#pragma unroll
      for (int j = 0; j < 2; ++j)
        bfr[j] = *(const s16x8*)(Bs + (wn * 32 + j * 16 + l15) * 64 + ((quad + 4 * kk) ^ sx) * 8);
#pragma unroll
      for (int i = 0; i < 4; ++i)
#pragma unroll
        for (int j = 0; j < 2; ++j)
          acc[i][j] = __builtin_amdgcn_mfma_f32_16x16x32_bf16(af[i], bfr[j], acc[i][j], 0, 0, 0);
    }
  }

  const int row0 = bm * 128 + wm * 64 + quad * 4;
  const int col0 = bn * 64 + wn * 32 + l15;
#pragma unroll
  for (int i = 0; i < 4; ++i)
#pragma unroll
    for (int j = 0; j < 2; ++j)
#pragma unroll
      for (int r = 0; r < 4; ++r)
        C[(size_t)(row0 + i * 16 + r) * N + (col0 + j * 16)] = acc[i][j][r];
}

// ---------------- flash attention v6: S^T formulation + double-buffered K/V ----------------
// v5 structure was {barrier; stage K/V; barrier(vmcnt0 drain); compute} per tile:
// full load latency serial with compute (MfmaUtil 12%, VALUBusy 29%, both idle most
// of the time). v6 = T3 minimum 2-phase: Ks/Vs double-buffered, stage tile j+1
// issued BEFORE computing tile j, ONE barrier per tile. The compiler's automatic
// s_waitcnt vmcnt(0) lgkmcnt(0) before s_barrier is exactly the depth-1 pipeline
// wait: load latency overlaps softmax+MFMA of current tile.
// Hazards: end-of-iter lgkmcnt(0)+barrier completes all ds_reads of buf[c] before
// iter i+1 overwrites it; Pw/qf traffic is wave-private rows (DS ops in-order per
// wave). LDS 48 KB/block (<=64 KB limit).
__global__ __launch_bounds__(512) void attn_kernel(const unsigned short* __restrict__ qkv,
                                                   const unsigned short* __restrict__ Vt,
                                                   unsigned short* __restrict__ Y) {
  __shared__ unsigned short Qs[128 * 64];     // Q tile, then wave-private P strips
  __shared__ unsigned short Ks[2][64 * 64];   // double-buffered K tiles
  __shared__ unsigned short Vs[2][64 * 64];   // double-buffered Vt tiles (rows=d, cols=keys)
  const int tid = threadIdx.x;
  const int wave = tid >> 6, lane = tid & 63;
  const int l15 = lane & 15, quad = lane >> 4;
  const int sx = l15 & 7, sx2 = sx << 1;

  const int p = blockIdx.x;
  const int r_ = p >> 8, c_ = p & 255;
  const int m_ = c_ & 15, g_ = c_ >> 4;
  const int bh = g_ + 16 * r_;
  const int lq = r_ ? (15 - m_) : m_;
  const int q0 = lq * 128;
  const int b = bh >> 4, h = bh & 15;
  const size_t base = (size_t)b * 2048 * 3072 + h * 64;
  const size_t vbase = (size_t)bh * 64 * 2048;

  // staging coords (one lds16 per thread per K-tile / per V-tile)
  const int srow = tid >> 3, scc = tid & 7;
  const int skc = (scc ^ (srow & 7)) * 8;

#pragma unroll
  for (int s = 0; s < 2; ++s) {
    int cid = tid + s * 512;
    int row = cid >> 3, cc = cid & 7;
    int kc = (cc ^ (row & 7)) * 8;
    load_lds16(qkv + base + (size_t)(q0 + row) * 3072 + kc, Qs + cid * 8);
  }
  // stage K/V tile 0 into buffer 0 (drained by the same prologue barrier)
  load_lds16(qkv + base + (size_t)srow * 3072 + 1024 + skc, Ks[0] + tid * 8);
  load_lds16(Vt + vbase + (size_t)srow * 2048 + skc, Vs[0] + tid * 8);
  __syncthreads();

  s16x8 qf[2];
  qf[0] = *(const s16x8*)(Qs + (wave * 16 + l15) * 64 + ((quad    ) ^ sx) * 8);
  qf[1] = *(const s16x8*)(Qs + (wave * 16 + l15) * 64 + ((quad + 4) ^ sx) * 8);

  f32x4 o[4] = {};
  float m_i = -1e30f, l_i = 0.f;
  const float kScale = 0.125f * 1.44269504f;  // 1/sqrt(64) * log2(e)
  const int qrow_w0 = q0 + wave * 16;
  const int qrow = qrow_w0 + l15;             // this lane's q-row
  unsigned short* Pw = Qs + wave * 16 * 64;   // wave-private P strip [16 qrows][64 keys]

  const int jmax = q0 + 64;                   // last tile start
  int cur = 0;

  for (int j0 = 0; j0 <= jmax; j0 += 64) {
    // issue next tile's stage first: its vmcnt drains at this iter's END barrier,
    // so the HBM/L2 latency hides under this tile's compute.
    if (j0 < jmax) {
      load_lds16(qkv + base + (size_t)(j0 + 64 + srow) * 3072 + 1024 + skc, Ks[cur ^ 1] + tid * 8);
      load_lds16(Vt + vbase + (size_t)srow * 2048 + (j0 + 64) + skc, Vs[cur ^ 1] + tid * 8);
    }

    if (j0 <= qrow_w0 + 15) {
      const unsigned short* Kc = Ks[cur];
      const unsigned short* Vc = Vs[cur];
      // S^T tiles: A = K rows, B = Q^T (same fragment data, swapped operand slots)
      f32x4 s[4];
#pragma unroll
      for (int nt = 0; nt < 4; ++nt) {
        const int kr = nt * 16 + l15;
        s16x8 kf0 = *(const s16x8*)(Kc + kr * 64 + ((quad    ) ^ sx) * 8);
        s16x8 kf1 = *(const s16x8*)(Kc + kr * 64 + ((quad + 4) ^ sx) * 8);
        f32x4 z = {};
        z = __builtin_amdgcn_mfma_f32_16x16x32_bf16(kf0, qf[0], z, 0, 0, 0);
        z = __builtin_amdgcn_mfma_f32_16x16x32_bf16(kf1, qf[1], z, 0, 0, 0);
        s[nt] = z;
      }

      // causal mask: key = j0 + nt*16 + quad*4 + r vs this lane's qrow
      if (j0 + 63 > qrow_w0) {
#pragma unroll
        for (int nt = 0; nt < 4; ++nt) {
          int key0 = j0 + nt * 16 + quad * 4;
#pragma unroll
          for (int r = 0; r < 4; ++r)
            if (key0 + r > qrow) s[nt][r] = -3e38f;
        }
      }

      // online softmax: per-lane row; tree max (fuses to v_max3), reduce over quads
      float t0 = fmaxf(fmaxf(s[0][0], s[0][1]), fmaxf(s[0][2], s[0][3]));
      float t1 = fmaxf(fmaxf(s[1][0], s[1][1]), fmaxf(s[1][2], s[1][3]));
      float t2 = fmaxf(fmaxf(s[2][0], s[2][1]), fmaxf(s[2][2], s[2][3]));
      float t3 = fmaxf(fmaxf(s[3][0], s[3][1]), fmaxf(s[3][2], s[3][3]));
      float tmax = fmaxf(fmaxf(t0, t1), fmaxf(t2, t3));
      tmax = fmaxf(tmax, __shfl_xor(tmax, 16, 64));
      tmax = fmaxf(tmax, __shfl_xor(tmax, 32, 64));
      float mn = fmaxf(m_i, tmax);
      float alpha = __builtin_amdgcn_exp2f((m_i - mn) * kScale);
      m_i = mn;
      const float mk = mn * kScale;
      float rs[4] = {0.f, 0.f, 0.f, 0.f};
#pragma unroll
      for (int nt = 0; nt < 4; ++nt)
#pragma unroll
        for (int r = 0; r < 4; ++r) {
          float pv = __builtin_amdgcn_exp2f(__builtin_fmaf(s[nt][r], kScale, -mk));
          s[nt][r] = pv;
          rs[nt] += pv;
        }
      float rsum = (rs[0] + rs[1]) + (rs[2] + rs[3]);
      rsum += __shfl_xor(rsum, 16, 64);
      rsum += __shfl_xor(rsum, 32, 64);
      l_i = l_i * alpha + rsum;
#pragma unroll
      for (int dt = 0; dt < 4; ++dt)
#pragma unroll
        for (int r = 0; r < 4; ++r)
          o[dt][r] *= alpha;

      // P row l15, cols nt*16+quad*4..+3 -> one b64 per nt (8B-chunk XOR swizzle)
#pragma unroll
      for (int nt = 0; nt < 4; ++nt) {
        u32x2 pk;
        pk.x = pack_bf2(s[nt][0], s[nt][1]);
        pk.y = pack_bf2(s[nt][2], s[nt][3]);
        int phys = (nt * 4 + quad) ^ sx2;
        *(u32x2*)(Pw + l15 * 64 + phys * 4) = pk;
      }

      // B-frags: P^T[k=kk*32+quad*8+j][qrow=l15] = row l15, 8 contiguous cols
      s16x8 pf[2];
      pf[0] = *(const s16x8*)(Pw + l15 * 64 + (((quad * 2)    ) ^ sx2) * 4);
      pf[1] = *(const s16x8*)(Pw + l15 * 64 + (((quad * 2) + 8) ^ sx2) * 4);

      // O^T += V^T · P^T  (A = vf, unchanged reads)
#pragma unroll
      for (int dt = 0; dt < 4; ++dt) {
        const int vr = dt * 16 + l15;
        s16x8 vf0 = *(const s16x8*)(Vc + vr * 64 + ((quad    ) ^ sx) * 8);
        s16x8 vf1 = *(const s16x8*)(Vc + vr * 64 + ((quad + 4) ^ sx) * 8);
        o[dt] = __builtin_amdgcn_mfma_f32_16x16x32_bf16(vf0, pf[0], o[dt], 0, 0, 0);
        o[dt] = __builtin_amdgcn_mfma_f32_16x16x32_bf16(vf1, pf[1], o[dt], 0, 0, 0);
      }
    }

    __syncthreads();   // drains: this iter's ds_reads (buffer reuse) + next tile's stage
    cur ^= 1;
  }

  const float inv = 1.0f / l_i;
  const size_t yoff = (size_t)(b * 2048 + qrow) * 1024 + h * 64 + quad * 4;
#pragma unroll
  for (int dt = 0; dt < 4; ++dt) {
    u16x4 pk;
#pragma unroll
    for (int r = 0; r < 4; ++r) pk[r] = f2bf(o[dt][r] * inv);
    *(u16x4*)(Y + yoff + dt * 16) = pk;
  }
}

extern "C" void kernel_launch(void* const* d_in, const int* in_sizes, int n_in,
                              void* d_out, int out_size, void* d_ws, size_t ws_size,
                              hipStream_t stream) {
  const float* x      = (const float*)d_in[0];  // [2,2048,1024]
  const float* w_qkv  = (const float*)d_in[1];  // [1024,3072]
  const float* w_proj = (const float*)d_in[2];  // [1024,1024]
  char* ws = (char*)d_ws;
  unsigned short* xb     = (unsigned short*)(ws);                      //  8 MiB
  unsigned short* wqkvT  = (unsigned short*)(ws + (size_t)(8  << 20)); //  6 MiB
  unsigned short* wprojT = (unsigned short*)(ws + (size_t)(14 << 20)); //  2 MiB
  unsigned short* qkv    = (unsigned short*)(ws + (size_t)(16 << 20)); // 24 MiB
  unsigned short* y      = (unsigned short*)(ws + (size_t)(40 << 20)); //  8 MiB
  unsigned short* Vt     = (unsigned short*)(ws + (size_t)(48 << 20)); //  8 MiB

  prep_kernel<<<8192, 256, 0, stream>>>(x, w_qkv, w_proj, xb, wqkvT, wprojT);
  gemm_qkv<<<dim3(24, 32), 256, 0, stream>>>(xb, wqkvT, qkv, 4096, 3072, 1024);
  transpose_v<<<dim3(32, 32), 256, 0, stream>>>(qkv, Vt);
  attn_kernel<<<512, 512, 0, stream>>>(qkv, Vt, y);
  gemm_proj<<<dim3(16, 32), 256, 0, stream>>>(y, wprojT, (float*)d_out, 4096, 1024, 1024);
}